// Round 14
// baseline (661.163 us; speedup 1.0000x reference)
//
#include <hip/hip_runtime.h>
#include <hip/hip_bf16.h>

// Problem dims (fixed by reference)
#define BATCH 16384
#define TT    64
#define INF   48
#define FF    32
#define TFD   2048   // T*F   (GEMM1 K)
#define THD   8192   // T*H   (GEMM1 N)

typedef __attribute__((ext_vector_type(8))) short bf16x8;
typedef __attribute__((ext_vector_type(4))) short bf16x4;
typedef __attribute__((ext_vector_type(4))) short short4v;
typedef __attribute__((ext_vector_type(4))) float f32x4;

#define SCHED __builtin_amdgcn_sched_barrier(0)
#define VMW(n) asm volatile("s_waitcnt vmcnt(" #n ")" ::: "memory")

__device__ inline void gload_lds16(const void* g, void* l) {
  __builtin_amdgcn_global_load_lds((const __attribute__((address_space(1))) void*)g,
                                   (__attribute__((address_space(3))) void*)l, 16, 0, 0);
}

__device__ inline f32x4 mfma16x16x16_bf16(bf16x4 a, bf16x4 b, f32x4 c) {
#if __has_builtin(__builtin_amdgcn_mfma_f32_16x16x16bf16_1k)
  return __builtin_amdgcn_mfma_f32_16x16x16bf16_1k(a, b, c, 0, 0, 0);
#else
  asm("v_mfma_f32_16x16x16_bf16 %0, %1, %2, %0" : "+v"(c) : "v"(a), "v"(b));
  return c;
#endif
}

__device__ inline short f32_to_bf16_bits(float x) {
  __hip_bfloat16 h = __float2bfloat16(x);
  return *reinterpret_cast<short*>(&h);
}

// ---------------- prep kernels ----------------

// xsf: fragment-linear X. Slot (g64, t, bi, lane):
//   element j: bf16( x[g64*64 + bi*16 + (lane&15)][t][sidx[(lane>>4)*8 + j]] )
__global__ void gather_cast_frag(const float* __restrict__ x, const int* __restrict__ sidx,
                                 __hip_bfloat16* __restrict__ xsf) {
  __shared__ int sx[FF];
  if (threadIdx.x < FF) sx[threadIdx.x] = sidx[threadIdx.x];
  __syncthreads();
  const int b64 = blockIdx.x >> 2;          // 0..255
  const int tq  = blockIdx.x & 3;           // t-quarter
  for (int it = 0; it < 16; ++it) {
    const int slot = (tq * 16 + it) * 256 + threadIdx.x;   // ((t*4+bi)*64+l)
    const int t  = slot >> 8;
    const int bi = (slot >> 6) & 3;
    const int l  = slot & 63;
    const int lo = l & 15, hi = l >> 4;
    const int row = b64 * 64 + bi * 16 + lo;
    const float* rp = x + ((size_t)row * TT + t) * INF;
    bf16x8 v;
    #pragma unroll
    for (int j = 0; j < 8; ++j) v[j] = f32_to_bf16_bits(rp[sx[hi * 8 + j]]);
    *(bf16x8*)(xsf + ((size_t)b64 * 16384 + slot) * 8) = v;
  }
}

// W1t[n][k] = bf16(W1[k][n]);  W1: [TFD][THD] row-major. ushort4 stores.
__global__ void transpose_w1(const float* __restrict__ W1, __hip_bfloat16* __restrict__ W1t) {
  __shared__ float tile[64][65];
  const int k0 = blockIdx.x * 64;
  const int n0 = blockIdx.y * 64;
  const int tx = threadIdx.x & 63, ty = threadIdx.x >> 6;
  for (int r = ty; r < 64; r += 4)
    tile[r][tx] = W1[(size_t)(k0 + r) * THD + n0 + tx];
  __syncthreads();
  const int rn = threadIdx.x >> 4;          // 0..15
  const int kq = (threadIdx.x & 15) * 4;    // k-quad
  for (int rr = rn; rr < 64; rr += 16) {
    short4v v;
    #pragma unroll
    for (int i = 0; i < 4; ++i) v[i] = f32_to_bf16_bits(tile[kq + i][rr]);
    *(short4v*)(W1t + (size_t)(n0 + rr) * TFD + k0 + kq) = v;
  }
}

// w2t[f][n] = bf16( sum_t W2[n][t*32+f]*weight[t][f] );  beff[f] = bias[f] + sum_t b2[t*32+f]*weight[t][f]
__global__ void make_w2eff(const float* __restrict__ W2, const float* __restrict__ b2,
                           const float* __restrict__ weight, const float* __restrict__ bias,
                           __hip_bfloat16* __restrict__ w2t, float* __restrict__ beff) {
  const int n = blockIdx.x * 8 + (threadIdx.x >> 5);
  const int f = threadIdx.x & 31;
  const float* wr = W2 + (size_t)n * TFD;
  float s = 0.f;
  #pragma unroll 8
  for (int t = 0; t < TT; ++t) s += wr[t * FF + f] * weight[t * FF + f];
  w2t[(size_t)f * THD + n] = __float2bfloat16(s);
  if (blockIdx.x == 0 && threadIdx.x < FF) {
    float sb = bias[f];
    for (int t = 0; t < TT; ++t) sb += b2[t * FF + f] * weight[t * FF + f];
    beff[f] = sb;
  }
}

// ---------------- main fused GEMM ----------------
// r14 = r13 occupancy experiment with the SYNC BUG FIXED: barrier EVERY
// iteration (r13's barrier-every-2 with only 2-ahead staging raced: a
// reader at t+1 could hit LDS before another wave's S(t+1) drained, which
// only happens at that wave's end-of-t VMW(2); r9's every-2 was safe only
// because it staged 3 ahead). Everything else as r13:
// 256b x 256n block, 16 waves (4 wn x 4 wb), per-wave 64x64 out ->
// acc[4][4]=64 VGPR; __launch_bounds__(1024,4) caps VGPR 128 -> 4 waves/
// SIMD (2x TLP vs r9/r12's 2/SIMD which plateaued at MFMA+fetch serial).
// Both operands via gload_lds: per wave per K32 tile = 1 W-gload + 1
// X-gload, 8 ds_reads, 16 MFMA. W tile paired-row + XOR swizzle; X tile
// fragment-linear. 4 x 32KB buffers, stage 2 ahead.
// vmcnt ledger: end-of-t outstanding {S(t+1),S(t+2)} -> VMW(2) drains
// S(t+1) BEFORE the barrier, so post-barrier readers of tile t+1 are safe.
// Tails: t=62 VMW(0); t=63 none. Prologue: S0,S1 -> VMW(2) -> barrier.

__device__ inline void stage_w16(char* buf, const __hip_bfloat16* __restrict__ w1t,
                                 int n0, int k0, int wid, int l) {
  const int sub = l >> 3;
  const int c   = (l & 7) ^ sub;             // inverse chunk swizzle (rows%8 == sub)
  const int h   = c >> 2, kc = c & 3;
  const int r0  = wid * 8 + sub;             // LDS row 0..127 (2 logical n-rows each)
  const __hip_bfloat16* gw = w1t + (size_t)(n0 + 2 * r0 + h) * TFD + k0 + kc * 8;
  gload_lds16(gw, buf + wid * 1024);         // wave-uniform dst; HW adds lane*16
}

__device__ inline void stage_x16(char* bufX, const char* __restrict__ xg, int t, int wid, int l) {
  const int g = wid >> 2, bi = wid & 3;      // chunk index == wid
  const char* src = xg + (size_t)g * 262144 + ((t * 4 + bi) * 1024) + l * 16;
  gload_lds16(src, bufX + wid * 1024);
}

__global__ __launch_bounds__(1024, 4) void gemm_fused(
    const __hip_bfloat16* __restrict__ xsf,   // fragment-linear X
    const __hip_bfloat16* __restrict__ w1t,   // [THD][TFD]
    const float* __restrict__ b1,             // [THD]
    const __hip_bfloat16* __restrict__ w2t,   // [FF][THD] bf16
    float* __restrict__ partial)              // [8][BATCH][FF]
{
  __shared__ __align__(16) char lds[131072];  // 4 x (W 16KB + X 16KB)
  const int tid = threadIdx.x;
  const int wid = tid >> 6, l = tid & 63;     // 16 waves
  const int wn = wid >> 2, wb = wid & 3;      // n-quarter (4) x batch-quarter (4)
  const int lo = l & 15, hi = l >> 4;
  const int rl = lo >> 1;
  const int cofs = (((((lo & 1) << 2) | hi) ^ rl) << 4);
  const int strip = blockIdx.x & 7;           // strip == XCD -> W slice L2-resident
  const int bt = blockIdx.x >> 3;             // 0..63
  const int b0 = bt * 256;

  const int wbase = ((wn << 5) + rl) * 128 + cofs;   // + mi*1024
  const int xoffr = 16384 + (wb << 12) + l * 16;     // + bi*1024
  const char* xg  = (const char*)xsf + (size_t)(bt * 4) * 262144;

  f32x4 acc2[2][4];                           // emb^T partial: [f-frag][batch-frag]
  #pragma unroll
  for (int fi = 0; fi < 2; ++fi)
    #pragma unroll
    for (int bi = 0; bi < 4; ++bi) { f32x4 z = {0.f,0.f,0.f,0.f}; acc2[fi][bi] = z; }

  for (int s = 0; s < 4; ++s) {
    const int n0 = strip * 1024 + s * 256;

    f32x4 acc[4][4];
    #pragma unroll
    for (int mi = 0; mi < 4; ++mi)
      #pragma unroll
      for (int bi = 0; bi < 4; ++bi) { f32x4 z = {0.f,0.f,0.f,0.f}; acc[mi][bi] = z; }

    // ---- prologue: stage tiles 0,1; drain tile0; barrier ----
    stage_w16(lds, w1t, n0, 0, wid, l);
    stage_x16(lds + 16384, xg, 0, wid, l);
    SCHED;
    stage_w16(lds + 32768, w1t, n0, 32, wid, l);
    stage_x16(lds + 32768 + 16384, xg, 1, wid, l);
    SCHED;
    VMW(2); SCHED;
    __builtin_amdgcn_s_barrier(); SCHED;

    for (int t = 0; t < 64; ++t) {
      char* buf = lds + (size_t)(t & 3) * 32768;
      if (t <= 61) {
        char* nbuf = lds + (size_t)((t + 2) & 3) * 32768;
        stage_w16(nbuf, w1t, n0, (t + 2) * 32, wid, l);
        stage_x16(nbuf + 16384, xg, t + 2, wid, l);
      }
      SCHED;
      // 8 ds_reads + 16 MFMA; compiler pipelines lgkmcnt fine-grained
      bf16x8 wf0 = *(const bf16x8*)(buf + wbase);
      bf16x8 wf1 = *(const bf16x8*)(buf + wbase + 1024);
      bf16x8 wf2 = *(const bf16x8*)(buf + wbase + 2048);
      bf16x8 wf3 = *(const bf16x8*)(buf + wbase + 3072);
      bf16x8 xf0 = *(const bf16x8*)(buf + xoffr);
      bf16x8 xf1 = *(const bf16x8*)(buf + xoffr + 1024);
      bf16x8 xf2 = *(const bf16x8*)(buf + xoffr + 2048);
      bf16x8 xf3 = *(const bf16x8*)(buf + xoffr + 3072);
      __builtin_amdgcn_s_setprio(1);
      acc[0][0] = __builtin_amdgcn_mfma_f32_16x16x32_bf16(wf0, xf0, acc[0][0], 0, 0, 0);
      acc[0][1] = __builtin_amdgcn_mfma_f32_16x16x32_bf16(wf0, xf1, acc[0][1], 0, 0, 0);
      acc[0][2] = __builtin_amdgcn_mfma_f32_16x16x32_bf16(wf0, xf2, acc[0][2], 0, 0, 0);
      acc[0][3] = __builtin_amdgcn_mfma_f32_16x16x32_bf16(wf0, xf3, acc[0][3], 0, 0, 0);
      acc[1][0] = __builtin_amdgcn_mfma_f32_16x16x32_bf16(wf1, xf0, acc[1][0], 0, 0, 0);
      acc[1][1] = __builtin_amdgcn_mfma_f32_16x16x32_bf16(wf1, xf1, acc[1][1], 0, 0, 0);
      acc[1][2] = __builtin_amdgcn_mfma_f32_16x16x32_bf16(wf1, xf2, acc[1][2], 0, 0, 0);
      acc[1][3] = __builtin_amdgcn_mfma_f32_16x16x32_bf16(wf1, xf3, acc[1][3], 0, 0, 0);
      acc[2][0] = __builtin_amdgcn_mfma_f32_16x16x32_bf16(wf2, xf0, acc[2][0], 0, 0, 0);
      acc[2][1] = __builtin_amdgcn_mfma_f32_16x16x32_bf16(wf2, xf1, acc[2][1], 0, 0, 0);
      acc[2][2] = __builtin_amdgcn_mfma_f32_16x16x32_bf16(wf2, xf2, acc[2][2], 0, 0, 0);
      acc[2][3] = __builtin_amdgcn_mfma_f32_16x16x32_bf16(wf2, xf3, acc[2][3], 0, 0, 0);
      acc[3][0] = __builtin_amdgcn_mfma_f32_16x16x32_bf16(wf3, xf0, acc[3][0], 0, 0, 0);
      acc[3][1] = __builtin_amdgcn_mfma_f32_16x16x32_bf16(wf3, xf1, acc[3][1], 0, 0, 0);
      acc[3][2] = __builtin_amdgcn_mfma_f32_16x16x32_bf16(wf3, xf2, acc[3][2], 0, 0, 0);
      acc[3][3] = __builtin_amdgcn_mfma_f32_16x16x32_bf16(wf3, xf3, acc[3][3], 0, 0, 0);
      __builtin_amdgcn_s_setprio(0);
      SCHED;
      if (t <= 61)      { VMW(2); }
      else if (t == 62) { VMW(0); }
      SCHED;
      __builtin_amdgcn_s_barrier(); SCHED;
    }

    // ---- epilogue: bias+relu+pack in regs, GEMM2 on matrix pipe ----
    #pragma unroll
    for (int mi = 0; mi < 4; ++mi) {
      const int nbase = n0 + (wn << 6) + (mi << 4);
      const float4 b1v = *(const float4*)(b1 + nbase + (hi << 2));
      bf16x4 p[4];
      #pragma unroll
      for (int bi = 0; bi < 4; ++bi) {
        bf16x4 pk;
        #pragma unroll
        for (int j = 0; j < 4; ++j) {
          float v = acc[mi][bi][j] + ((const float*)&b1v)[j];
          v = v > 0.f ? v : 0.f;
          pk[j] = f32_to_bf16_bits(v);
        }
        p[bi] = pk;
      }
      bf16x4 a2[2];
      #pragma unroll
      for (int fi = 0; fi < 2; ++fi)
        a2[fi] = *(const bf16x4*)(w2t + (size_t)(fi * 16 + lo) * THD + nbase + (hi << 2));
      #pragma unroll
      for (int fi = 0; fi < 2; ++fi)
        #pragma unroll
        for (int bi = 0; bi < 4; ++bi)
          acc2[fi][bi] = mfma16x16x16_bf16(a2[fi], p[bi], acc2[fi][bi]);
    }
  }

  // ---- 4-way merge across wn via LDS (all buffers dead), then store ----
  float* sm = (float*)lds;                    // 3 slabs x 32KB = 96KB
  __syncthreads();                            // all K-loop LDS reads retired
  if (wn != 0) {
    float* slab = sm + (size_t)(wn - 1) * 8192;   // 8192 floats = 32KB
    #pragma unroll
    for (int fi = 0; fi < 2; ++fi)
      #pragma unroll
      for (int bi = 0; bi < 4; ++bi)
        *(f32x4*)(slab + ((wb << 6) + (bi << 4) + lo) * 32 + fi * 16 + (hi << 2)) = acc2[fi][bi];
  }
  __syncthreads();
  if (wn == 0) {
    #pragma unroll
    for (int fi = 0; fi < 2; ++fi)
      #pragma unroll
      for (int bi = 0; bi < 4; ++bi) {
        const int off = ((wb << 6) + (bi << 4) + lo) * 32 + fi * 16 + (hi << 2);
        f32x4 v = acc2[fi][bi];
        v = v + *(const f32x4*)(sm + off);
        v = v + *(const f32x4*)(sm + 8192 + off);
        v = v + *(const f32x4*)(sm + 16384 + off);
        *(f32x4*)(partial + ((size_t)strip * BATCH + b0 + (wb << 6) + (bi << 4) + lo) * FF + fi * 16 + (hi << 2)) = v;
      }
  }
}

// out[b][f] = beff[f] + sum_c partial[c][b][f]
__global__ void reduce_partial(const float* __restrict__ partial, const float* __restrict__ beff,
                               float* __restrict__ out) {
  const int idx = blockIdx.x * 256 + threadIdx.x;
  float s = beff[idx & 31];
  #pragma unroll
  for (int c = 0; c < 8; ++c) s += partial[(size_t)c * BATCH * FF + idx];
  out[idx] = s;
}

// ---------------- launch ----------------

extern "C" void kernel_launch(void* const* d_in, const int* in_sizes, int n_in,
                              void* d_out, int out_size, void* d_ws, size_t ws_size,
                              hipStream_t stream) {
  const float* x      = (const float*)d_in[0];
  const float* W1     = (const float*)d_in[1];
  const float* b1     = (const float*)d_in[2];
  const float* W2     = (const float*)d_in[3];
  const float* b2     = (const float*)d_in[4];
  const float* weight = (const float*)d_in[5];
  const float* bias   = (const float*)d_in[6];
  const int*   sidx   = (const int*)d_in[7];

  char* ws = (char*)d_ws;
  // ws layout (bytes):
  //   xsf     [16384][2048] bf16 (frag-linear) : 0 .. 67108864
  //   w1t     [8192][2048]  bf16 :  67108864 .. 100663296
  //   w2t     [32][8192]    bf16 : 100663296 .. 101187584
  //   beff    [32]          f32  : 101187584 .. 101187712
  //   partial [8][16384][32] f32 : 101188608 .. 117965824
  __hip_bfloat16* xsf  = (__hip_bfloat16*)ws;
  __hip_bfloat16* w1t  = (__hip_bfloat16*)(ws + 67108864);
  __hip_bfloat16* w2t  = (__hip_bfloat16*)(ws + 100663296);
  float*          beff = (float*)(ws + 101187584);
  float*          part = (float*)(ws + 101188608);

  hipLaunchKernelGGL(gather_cast_frag, dim3(1024), dim3(256), 0, stream, x, sidx, xsf);
  hipLaunchKernelGGL(transpose_w1, dim3(32, 128), dim3(256), 0, stream, W1, w1t);
  hipLaunchKernelGGL(make_w2eff,   dim3(1024),    dim3(256), 0, stream, W2, b2, weight, bias, w2t, beff);
  hipLaunchKernelGGL(gemm_fused,   dim3(512),     dim3(1024), 0, stream, xsf, w1t, b1, w2t, part);
  hipLaunchKernelGGL(reduce_partial, dim3(2048),  dim3(256), 0, stream, part, beff, (float*)d_out);
}